// Round 1
// baseline (2562.621 us; speedup 1.0000x reference)
//
#include <hip/hip_runtime.h>
#include <hip/hip_bf16.h>

// Problem constants (validated against in_sizes at runtime where cheap)
#define D_DIM 128
#define KT 128
#define JF 64

// ---------------------------------------------------------------------------
// Edge pass: build N[i,k] counts, Xi = segsum(edge_x, i), Xk = segsum(edge_x, k),
// cntw = per-k edge counts. Xk / cntw privatized in LDS (only 128 segments).
// ---------------------------------------------------------------------------
__global__ void __launch_bounds__(256) edge_pass_kernel(
    const float* __restrict__ edge_x, const int* __restrict__ edge_i,
    const int* __restrict__ edge_k, float* __restrict__ Xi, float* __restrict__ Xk,
    unsigned* __restrict__ Nmat, unsigned* __restrict__ cntw, int E, int epb)
{
    __shared__ float xk_s[KT * JF];      // 32 KB
    __shared__ unsigned cw_s[KT];
    for (int t = threadIdx.x; t < KT * JF; t += 256) xk_s[t] = 0.f;
    if (threadIdx.x < KT) cw_s[threadIdx.x] = 0u;
    __syncthreads();
    const int wid = threadIdx.x >> 6, lane = threadIdx.x & 63;
    const long base = (long)blockIdx.x * epb;
    for (int c = wid; c < epb; c += 4) {
        long e = base + c;
        if (e >= (long)E) break;
        int i = edge_i[e], k = edge_k[e];
        float x = edge_x[e * 64 + lane];
        unsafeAtomicAdd(&Xi[(long)i * 64 + lane], x);
        unsafeAtomicAdd(&xk_s[k * 64 + lane], x);
        if (lane == 0) {
            atomicAdd(&Nmat[(long)i * 128 + k], 1u);
            atomicAdd(&cw_s[k], 1u);
        }
    }
    __syncthreads();
    for (int t = threadIdx.x; t < KT * JF; t += 256) {
        float v = xk_s[t];
        if (v != 0.f) unsafeAtomicAdd(&Xk[t], v);
    }
    if (threadIdx.x < KT && cw_s[threadIdx.x]) atomicAdd(&cntw[threadIdx.x], cw_s[threadIdx.x]);
}

// cnt_raw[i] = sum_k N[i,k]; invcnt = 1/max(cnt,1). One wave per row.
__global__ void cnt_kernel(const unsigned* __restrict__ Nmat, float* __restrict__ cntraw,
                           float* __restrict__ invcnt, int nNodes)
{
    int row = blockIdx.x * 4 + (threadIdx.x >> 6);
    int lane = threadIdx.x & 63;
    if (row >= nNodes) return;
    const unsigned* r = Nmat + (long)row * 128;
    unsigned s = r[lane] + r[lane + 64];
    #pragma unroll
    for (int o = 32; o; o >>= 1) s += __shfl_down(s, o, 64);
    if (lane == 0) {
        float c = (float)s;
        cntraw[row] = c;
        invcnt[row] = 1.f / fmaxf(c, 1.f);
    }
}

// ---------------------------------------------------------------------------
// layerA: U_out = relu( U_in@uWt + (N@P2 + Xi@P3)*invcnt + ub + flag*ebx )
// Tiled GEMM: 64 nodes/block, concat-K of 320 handled as 5 tiles of 64.
// ---------------------------------------------------------------------------
__global__ void __launch_bounds__(256) layerA_kernel(
    const float* __restrict__ U_in, const unsigned* __restrict__ Nmat,
    const float* __restrict__ Xi, const float* __restrict__ cntraw,
    const float* __restrict__ invcnt, const float* __restrict__ uWt,
    const float* __restrict__ P2, const float* __restrict__ P3,
    const float* __restrict__ ub_l, const float* __restrict__ ebx,
    float* __restrict__ U_out, int nNodes)
{
    __shared__ __align__(16) float A_s[64][68];    // [jj][m], padded
    __shared__ __align__(16) float B_s[64][132];   // [jj][d], padded
    const int tid = threadIdx.x;
    const int tm = tid >> 5;    // 0..7   (node group)
    const int td = tid & 31;    // 0..31  (dim group, 4 dims each)
    float acc[8][4];
    #pragma unroll
    for (int a = 0; a < 8; ++a) { acc[a][0]=0.f; acc[a][1]=0.f; acc[a][2]=0.f; acc[a][3]=0.f; }
    const int nodeBase = blockIdx.x * 64;

    for (int tile = 0; tile < 5; ++tile) {
        __syncthreads();
        const float* Bsrc;
        if (tile == 0)      Bsrc = uWt;
        else if (tile == 1) Bsrc = uWt + 64 * 128;
        else if (tile == 2) Bsrc = P2;
        else if (tile == 3) Bsrc = P2 + 64 * 128;
        else                Bsrc = P3;
        #pragma unroll
        for (int it = 0; it < 32; ++it) {
            int t = tid + it * 256;
            int r = t >> 7, c = t & 127;
            B_s[r][c] = Bsrc[r * 128 + c];
        }
        #pragma unroll
        for (int it = 0; it < 16; ++it) {
            int t = tid + it * 256;
            int m = t >> 6, jj = t & 63;
            int node = nodeBase + m;
            float v = 0.f;
            if (node < nNodes) {
                if (tile < 2)      v = U_in[(long)node * 128 + tile * 64 + jj];
                else if (tile < 4) v = (float)Nmat[(long)node * 128 + (tile - 2) * 64 + jj] * invcnt[node];
                else               v = Xi[(long)node * 64 + jj] * invcnt[node];
            }
            A_s[jj][m] = v;
        }
        __syncthreads();
        #pragma unroll 4
        for (int jj = 0; jj < 64; ++jj) {
            float4 bv = *(const float4*)&B_s[jj][td * 4];
            float4 a0 = *(const float4*)&A_s[jj][tm * 8];
            float4 a1 = *(const float4*)&A_s[jj][tm * 8 + 4];
            float av[8] = {a0.x, a0.y, a0.z, a0.w, a1.x, a1.y, a1.z, a1.w};
            #pragma unroll
            for (int a = 0; a < 8; ++a) {
                acc[a][0] += av[a] * bv.x;
                acc[a][1] += av[a] * bv.y;
                acc[a][2] += av[a] * bv.z;
                acc[a][3] += av[a] * bv.w;
            }
        }
    }
    const int d0 = td * 4;
    #pragma unroll
    for (int a = 0; a < 8; ++a) {
        int node = nodeBase + tm * 8 + a;
        if (node < nNodes) {
            float flag = (cntraw[node] > 0.f) ? 1.f : 0.f;
            float4 o;
            o.x = fmaxf(acc[a][0] + ub_l[d0 + 0] + flag * ebx[d0 + 0], 0.f);
            o.y = fmaxf(acc[a][1] + ub_l[d0 + 1] + flag * ebx[d0 + 1], 0.f);
            o.z = fmaxf(acc[a][2] + ub_l[d0 + 2] + flag * ebx[d0 + 2], 0.f);
            o.w = fmaxf(acc[a][3] + ub_l[d0 + 3] + flag * ebx[d0 + 3], 0.f);
            *(float4*)(U_out + (long)node * 128 + d0) = o;
        }
    }
}

// ---------------------------------------------------------------------------
// wmsgB: Wmsg[k][d] += sum_i N[i][k] * U[i][d]   (N^T @ U), register-blocked
// 8x8 per thread, LDS-staged 16-node groups, atomic flush per block.
// ---------------------------------------------------------------------------
__global__ void __launch_bounds__(256) wmsgB_kernel(
    const float* __restrict__ U, const unsigned* __restrict__ Nmat,
    float* __restrict__ Wmsg, int nodes_per_block, int nNodes)
{
    __shared__ __align__(16) float n_s[16][128];
    __shared__ __align__(16) float u_s[16][128];
    float acc[8][8];
    #pragma unroll
    for (int a = 0; a < 8; ++a)
        #pragma unroll
        for (int b = 0; b < 8; ++b) acc[a][b] = 0.f;
    const int kg = threadIdx.x >> 4;   // 0..15
    const int dg = threadIdx.x & 15;   // 0..15
    int base = blockIdx.x * nodes_per_block;
    int end = min(base + nodes_per_block, nNodes);
    for (int g = base; g < end; g += 16) {
        int cnt = min(16, end - g);
        __syncthreads();
        for (int t = threadIdx.x; t < 16 * 128; t += 256) {
            int r = t >> 7, c = t & 127;
            if (r < cnt) {
                n_s[r][c] = (float)Nmat[(long)(g + r) * 128 + c];
                u_s[r][c] = U[(long)(g + r) * 128 + c];
            }
        }
        __syncthreads();
        for (int r = 0; r < cnt; ++r) {
            float4 n0 = *(const float4*)&n_s[r][kg * 8];
            float4 n1 = *(const float4*)&n_s[r][kg * 8 + 4];
            float4 u0v = *(const float4*)&u_s[r][dg * 8];
            float4 u1v = *(const float4*)&u_s[r][dg * 8 + 4];
            float nv[8] = {n0.x, n0.y, n0.z, n0.w, n1.x, n1.y, n1.z, n1.w};
            float uv[8] = {u0v.x, u0v.y, u0v.z, u0v.w, u1v.x, u1v.y, u1v.z, u1v.w};
            #pragma unroll
            for (int a = 0; a < 8; ++a)
                #pragma unroll
                for (int b = 0; b < 8; ++b) acc[a][b] += nv[a] * uv[b];
        }
    }
    #pragma unroll
    for (int a = 0; a < 8; ++a)
        #pragma unroll
        for (int b = 0; b < 8; ++b)
            unsafeAtomicAdd(&Wmsg[(kg * 8 + a) * 128 + dg * 8 + b], acc[a][b]);
}

// Wmsgn[k][d] = (Wmsg[k][d] + Xk[k]@ep_W[:,d] + cntw[k]*ep_b[d]) / max(cntw,1)
__global__ void wmsg_fin_kernel(const float* __restrict__ Wmsg, const float* __restrict__ Xk,
                                const unsigned* __restrict__ cntw, const float* __restrict__ ep_W,
                                const float* __restrict__ ep_b, float* __restrict__ out)
{
    int idx = blockIdx.x * 256 + threadIdx.x;   // < 16384
    int kk = idx >> 7, d = idx & 127;
    float s = Wmsg[idx];
    const float* xk = Xk + kk * 64;
    #pragma unroll 8
    for (int j = 0; j < 64; ++j) s += xk[j] * ep_W[j * 128 + d];
    float c = (float)cntw[kk];
    s += c * ep_b[d];
    out[idx] = s / fmaxf(c, 1.f);
}

// Generic small GEMM: C = act(A@B [+ A2@B2] + bias [+ res]); one thread per output.
__global__ void gemm_kernel(const float* __restrict__ A, const float* __restrict__ B,
                            const float* __restrict__ A2, const float* __restrict__ B2,
                            const float* __restrict__ bias, const float* __restrict__ res,
                            float* __restrict__ C, int M, int N, int K, int K2, int act)
{
    int idx = blockIdx.x * 256 + threadIdx.x;
    if (idx >= M * N) return;
    int m = idx / N, n = idx - m * N;
    float s = bias ? bias[n] : 0.f;
    const float* a = A + (long)m * K;
    for (int k = 0; k < K; ++k) s += a[k] * B[(long)k * N + n];
    if (A2) {
        const float* a2 = A2 + (long)m * K2;
        for (int k = 0; k < K2; ++k) s += a2[k] * B2[(long)k * N + n];
    }
    if (res) s += res[idx];
    if (act) s = fmaxf(s, 0.f);
    C[idx] = s;
}

__global__ void add_kernel(const float* __restrict__ A, const float* __restrict__ B,
                           float* __restrict__ C, int n)
{
    int i = blockIdx.x * 256 + threadIdx.x;
    if (i < n) C[i] = A[i] + B[i];
}

// MHA over 128 tokens, H=2, dh=64. One block (128 threads) per query token.
__global__ void attn_kernel(const float* __restrict__ q, const float* __restrict__ kmat,
                            const float* __restrict__ vmat, float* __restrict__ outp)
{
    __shared__ float p_s[128];
    __shared__ float red_s[4];
    const int tok = blockIdx.x;
    const int t = threadIdx.x;
    const int lane = t & 63, wid = t >> 6;
    for (int h = 0; h < 2; ++h) {
        const float* qr = q + tok * 128 + h * 64;
        const float* kr = kmat + t * 128 + h * 64;
        float s = 0.f;
        #pragma unroll
        for (int d = 0; d < 64; ++d) s += qr[d] * kr[d];
        s *= 0.125f;
        float m = s;
        #pragma unroll
        for (int o = 32; o; o >>= 1) m = fmaxf(m, __shfl_down(m, o, 64));
        if (lane == 0) red_s[wid] = m;
        __syncthreads();
        m = fmaxf(red_s[0], red_s[1]);
        float ev = expf(s - m);
        float ss = ev;
        #pragma unroll
        for (int o = 32; o; o >>= 1) ss += __shfl_down(ss, o, 64);
        if (lane == 0) red_s[2 + wid] = ss;
        __syncthreads();
        float tot = red_s[2] + red_s[3];
        p_s[t] = ev / tot;
        __syncthreads();
        if (t < 64) {
            float o = 0.f;
            #pragma unroll 8
            for (int j = 0; j < 128; ++j) o += p_s[j] * vmat[j * 128 + h * 64 + t];
            outp[tok * 128 + h * 64 + t] = o;
        }
        __syncthreads();
    }
}

__global__ void ln_kernel(const float* __restrict__ x, const float* __restrict__ g,
                          const float* __restrict__ b, float* __restrict__ y)
{
    __shared__ float red_s[4];
    const int row = blockIdx.x, t = threadIdx.x, lane = t & 63, wid = t >> 6;
    float v = x[row * 128 + t];
    float s = v;
    #pragma unroll
    for (int o = 32; o; o >>= 1) s += __shfl_down(s, o, 64);
    if (lane == 0) red_s[wid] = s;
    __syncthreads();
    float mean = (red_s[0] + red_s[1]) * (1.f / 128.f);
    float d = v - mean;
    float q2 = d * d;
    #pragma unroll
    for (int o = 32; o; o >>= 1) q2 += __shfl_down(q2, o, 64);
    if (lane == 0) red_s[2 + wid] = q2;
    __syncthreads();
    float var = (red_s[2] + red_s[3]) * (1.f / 128.f);
    y[row * 128 + t] = d * rsqrtf(var + 1e-5f) * g[t] + b[t];
}

// decode: out[t] = sigmoid( sum_d U2[i][d]*Wf[k][d]*V[j][d] + bias )
__global__ void __launch_bounds__(256) decode_kernel(
    const int* __restrict__ idx_i, const int* __restrict__ idx_j, const int* __restrict__ idx_k,
    const float* __restrict__ U2, const float* __restrict__ Wf, const float* __restrict__ V,
    const float* __restrict__ bias, float* __restrict__ out, int n)
{
    int t = blockIdx.x * 256 + threadIdx.x;
    if (t >= n) return;
    int i = idx_i[t], j = idx_j[t], kk = idx_k[t];
    const float4* u = (const float4*)(U2 + (long)i * 128);
    const float4* w = (const float4*)(Wf + kk * 128);
    const float4* vv = (const float4*)(V + j * 128);
    float s = 0.f;
    #pragma unroll
    for (int c = 0; c < 32; ++c) {
        float4 a = u[c], b = w[c], d = vv[c];
        s += a.x * b.x * d.x + a.y * b.y * d.y + a.z * b.z * d.z + a.w * b.w * d.w;
    }
    s += bias[0];
    out[t] = 1.f / (1.f + expf(-s));
}

// ---------------------------------------------------------------------------
extern "C" void kernel_launch(void* const* d_in, const int* in_sizes, int n_in,
                              void* d_out, int out_size, void* d_ws, size_t ws_size,
                              hipStream_t stream)
{
    const float* edge_x = (const float*)d_in[0];
    const int*   edge_i = (const int*)d_in[1];
    const int*   edge_k = (const int*)d_in[2];
    const int*   idx_i  = (const int*)d_in[3];
    const int*   idx_j  = (const int*)d_in[4];
    const int*   idx_k  = (const int*)d_in[5];
    const float* u0   = (const float*)d_in[6];
    const float* w0   = (const float*)d_in[7];
    const float* ep_W = (const float*)d_in[8];
    const float* ep_b = (const float*)d_in[9];
    const float* uW   = (const float*)d_in[10];
    const float* ub   = (const float*)d_in[11];
    const float* wW   = (const float*)d_in[12];
    const float* wb   = (const float*)d_in[13];
    const float* pos  = (const float*)d_in[14];
    const float* Wq = (const float*)d_in[15];
    const float* Wk = (const float*)d_in[16];
    const float* Wv = (const float*)d_in[17];
    const float* bq = (const float*)d_in[18];
    const float* bk = (const float*)d_in[19];
    const float* bv = (const float*)d_in[20];
    const float* Wo = (const float*)d_in[21];
    const float* bo = (const float*)d_in[22];
    const float* ln1_g = (const float*)d_in[23];
    const float* ln1_b = (const float*)d_in[24];
    const float* f_W1 = (const float*)d_in[25];
    const float* f_b1 = (const float*)d_in[26];
    const float* f_W2 = (const float*)d_in[27];
    const float* f_b2 = (const float*)d_in[28];
    const float* ln2_g = (const float*)d_in[29];
    const float* ln2_b = (const float*)d_in[30];
    const float* Vmat = (const float*)d_in[31];
    const float* bias = (const float*)d_in[32];

    const int E   = in_sizes[1];
    const int NTt = in_sizes[3];
    const int nNodes = in_sizes[6] / D_DIM;

    char* ws = (char*)d_ws;
    size_t off = 0;
    auto alloc = [&](size_t bytes) -> char* {
        char* p = ws + off;
        off = (off + bytes + 255) & ~(size_t)255;
        return p;
    };
    // zero-initialized region first (single memset)
    unsigned* Nmat  = (unsigned*)alloc((size_t)nNodes * 128 * 4);
    float*    Xi    = (float*)alloc((size_t)nNodes * 64 * 4);
    float*    Xkseg = (float*)alloc(128 * 64 * 4);
    unsigned* cntw  = (unsigned*)alloc(512);
    float*    Wmsg0 = (float*)alloc(65536);
    float*    Wmsg1 = (float*)alloc(65536);
    size_t zeroBytes = off;
    // rest (written before read)
    float* cntraw = (float*)alloc((size_t)nNodes * 4);
    float* invcnt = (float*)alloc((size_t)nNodes * 4);
    float* U1 = (float*)alloc((size_t)nNodes * 128 * 4);
    float* U2 = (float*)alloc((size_t)nNodes * 128 * 4);
    float* W1 = (float*)alloc(65536);
    float* W2 = (float*)alloc(65536);
    float* P2_0 = (float*)alloc(65536);
    float* P2_1 = (float*)alloc(65536);
    float* P3_0 = (float*)alloc(32768);
    float* P3_1 = (float*)alloc(32768);
    float* ebx0 = (float*)alloc(512);
    float* ebx1 = (float*)alloc(512);
    float* Wmsgn0 = (float*)alloc(65536);
    float* Wmsgn1 = (float*)alloc(65536);
    float* Xmat  = (float*)alloc(65536);
    float* qm    = (float*)alloc(65536);
    float* km    = (float*)alloc(65536);
    float* vm    = (float*)alloc(65536);
    float* attnO = (float*)alloc(65536);
    float* pre1  = (float*)alloc(65536);
    float* H1m   = (float*)alloc(65536);
    float* F1    = (float*)alloc(262144);
    float* pre2  = (float*)alloc(65536);
    float* Wfm   = (float*)alloc(65536);

    const float* uWt0 = uW;
    const float* uWb0 = uW + 128 * 128;
    const float* uWt1 = uW + 256 * 128;
    const float* uWb1 = uW + 256 * 128 + 128 * 128;
    const float* wWt0 = wW;
    const float* wWb0 = wW + 128 * 128;
    const float* wWt1 = wW + 256 * 128;
    const float* wWb1 = wW + 256 * 128 + 128 * 128;

    hipMemsetAsync(d_ws, 0, zeroBytes, stream);

    int epb = (E + 1023) / 1024;
    edge_pass_kernel<<<1024, 256, 0, stream>>>(edge_x, edge_i, edge_k, Xi, Xkseg, Nmat, cntw, E, epb);
    cnt_kernel<<<(nNodes + 3) / 4, 256, 0, stream>>>(Nmat, cntraw, invcnt, nNodes);

    // ---- layer 0 ----
    gemm_kernel<<<64, 256, 0, stream>>>(w0, uWb0, nullptr, nullptr, nullptr, nullptr, P2_0, 128, 128, 128, 0, 0);
    gemm_kernel<<<32, 256, 0, stream>>>(ep_W, uWb0, nullptr, nullptr, nullptr, nullptr, P3_0, 64, 128, 128, 0, 0);
    gemm_kernel<<<1, 256, 0, stream>>>(ep_b, uWb0, nullptr, nullptr, nullptr, nullptr, ebx0, 1, 128, 128, 0, 0);
    int npb = (nNodes + 255) / 256;
    wmsgB_kernel<<<256, 256, 0, stream>>>(u0, Nmat, Wmsg0, npb, nNodes);
    layerA_kernel<<<(nNodes + 63) / 64, 256, 0, stream>>>(u0, Nmat, Xi, cntraw, invcnt,
                                                          uWt0, P2_0, P3_0, ub, ebx0, U1, nNodes);
    wmsg_fin_kernel<<<64, 256, 0, stream>>>(Wmsg0, Xkseg, cntw, ep_W, ep_b, Wmsgn0);
    gemm_kernel<<<64, 256, 0, stream>>>(w0, wWt0, Wmsgn0, wWb0, wb, nullptr, W1, 128, 128, 128, 128, 1);

    // ---- layer 1 ----
    gemm_kernel<<<64, 256, 0, stream>>>(W1, uWb1, nullptr, nullptr, nullptr, nullptr, P2_1, 128, 128, 128, 0, 0);
    gemm_kernel<<<32, 256, 0, stream>>>(ep_W, uWb1, nullptr, nullptr, nullptr, nullptr, P3_1, 64, 128, 128, 0, 0);
    gemm_kernel<<<1, 256, 0, stream>>>(ep_b, uWb1, nullptr, nullptr, nullptr, nullptr, ebx1, 1, 128, 128, 0, 0);
    wmsgB_kernel<<<256, 256, 0, stream>>>(U1, Nmat, Wmsg1, npb, nNodes);
    layerA_kernel<<<(nNodes + 63) / 64, 256, 0, stream>>>(U1, Nmat, Xi, cntraw, invcnt,
                                                          uWt1, P2_1, P3_1, ub + 128, ebx1, U2, nNodes);
    wmsg_fin_kernel<<<64, 256, 0, stream>>>(Wmsg1, Xkseg, cntw, ep_W, ep_b, Wmsgn1);
    gemm_kernel<<<64, 256, 0, stream>>>(W1, wWt1, Wmsgn1, wWb1, wb + 128, nullptr, W2, 128, 128, 128, 128, 1);

    // ---- TimeRefine ----
    add_kernel<<<64, 256, 0, stream>>>(W2, pos, Xmat, 128 * 128);
    gemm_kernel<<<64, 256, 0, stream>>>(Xmat, Wq, nullptr, nullptr, bq, nullptr, qm, 128, 128, 128, 0, 0);
    gemm_kernel<<<64, 256, 0, stream>>>(Xmat, Wk, nullptr, nullptr, bk, nullptr, km, 128, 128, 128, 0, 0);
    gemm_kernel<<<64, 256, 0, stream>>>(Xmat, Wv, nullptr, nullptr, bv, nullptr, vm, 128, 128, 128, 0, 0);
    attn_kernel<<<128, 128, 0, stream>>>(qm, km, vm, attnO);
    gemm_kernel<<<64, 256, 0, stream>>>(attnO, Wo, nullptr, nullptr, bo, Xmat, pre1, 128, 128, 128, 0, 0);
    ln_kernel<<<128, 128, 0, stream>>>(pre1, ln1_g, ln1_b, H1m);
    gemm_kernel<<<256, 256, 0, stream>>>(H1m, f_W1, nullptr, nullptr, f_b1, nullptr, F1, 128, 512, 128, 0, 1);
    gemm_kernel<<<64, 256, 0, stream>>>(F1, f_W2, nullptr, nullptr, f_b2, H1m, pre2, 128, 128, 512, 0, 0);
    ln_kernel<<<128, 128, 0, stream>>>(pre2, ln2_g, ln2_b, Wfm);

    // ---- decode ----
    decode_kernel<<<(NTt + 255) / 256, 256, 0, stream>>>(idx_i, idx_j, idx_k, U2, Wfm, Vmat,
                                                         bias, (float*)d_out, NTt);
}